// Round 13
// baseline (189.745 us; speedup 1.0000x reference)
//
#include <hip/hip_runtime.h>

typedef unsigned short u16;
typedef u16 ushort8 __attribute__((ext_vector_type(8)));
typedef __bf16 bf16x8 __attribute__((ext_vector_type(8)));
typedef float f32x4 __attribute__((ext_vector_type(4)));
typedef long long ll;

__device__ __forceinline__ u16 f2bf(float f) {
    unsigned u = __builtin_bit_cast(unsigned, f);
    u += 0x7FFFu + ((u >> 16) & 1u);
    return (u16)(u >> 16);
}
__device__ __forceinline__ float bf2f(u16 h) {
    return __builtin_bit_cast(float, (unsigned)h << 16);
}

// async global->LDS, 16B per lane, wave-uniform LDS base + lane*16
#define GLOAD16(dst, src) \
    __builtin_amdgcn_global_load_lds( \
        (const __attribute__((address_space(1))) void*)(src), \
        (__attribute__((address_space(3))) void*)(dst), 16, 0, 0)

// ---------------------------------------------------------------------------
// prep_all: one launch for all independent preprocessing (proven).
// ---------------------------------------------------------------------------
__global__ __launch_bounds__(256) void prep_all(
    const float* __restrict__ Wq, const float* __restrict__ Wk,
    const float* __restrict__ Wv, u16* __restrict__ WqkvT,
    const float* __restrict__ W1, u16* __restrict__ w1T,
    const float* __restrict__ W2, u16* __restrict__ w2T,
    const float* __restrict__ x, u16* __restrict__ xb,
    const float* __restrict__ bq, const float* __restrict__ bk,
    const float* __restrict__ bv, float* __restrict__ bqkv)
{
    __shared__ u16 tile[64][65];
    const int bid = blockIdx.x;
    const int tid = threadIdx.x;

    if (bid < 1024) {
        int idx = bid * 256 + tid;              // 0 .. 512*512-1
        int e = idx & 511, d = idx >> 9;
        float sq = 0.f, sk = 0.f, sv = 0.f;
#pragma unroll
        for (int h = 0; h < 8; ++h) {
            ll off = (ll)(h * 512 + d) * 512 + e;
            sq += Wq[off]; sk += Wk[off]; sv += Wv[off];
        }
        int o = e * 512 + d;
        WqkvT[o] = f2bf(sq);
        WqkvT[512 * 512 + o] = f2bf(sk);
        WqkvT[1024 * 512 + o] = f2bf(sv);
    } else if (bid < 1536) {
        const bool isW1 = bid < 1280;
        const int id = isW1 ? (bid - 1024) : (bid - 1280);
        const int bx = isW1 ? (id & 7) : (id & 31);
        const int by = isW1 ? (id >> 3) : (id >> 5);
        const float* in = isW1 ? W1 : W2;
        u16* out = isW1 ? w1T : w2T;
        const int ldin = isW1 ? 2048 : 512;
        const int ldout = isW1 ? 512 : 2048;
        const int r0 = bx * 64, c0 = by * 64;
#pragma unroll
        for (int i = 0; i < 16; ++i) {
            int lin = tid + i * 256;
            int rr = lin >> 6, cc = lin & 63;
            tile[rr][cc] = f2bf(in[(ll)(r0 + rr) * ldin + (c0 + cc)]);
        }
        __syncthreads();
#pragma unroll
        for (int i = 0; i < 16; ++i) {
            int lin = tid + i * 256;
            int rr = lin >> 6, cc = lin & 63;
            out[(ll)(c0 + rr) * ldout + (r0 + cc)] = tile[cc][rr];
        }
    } else if (bid < 3584) {
        ll i = ((ll)(bid - 1536) * 256 + tid) * 8;
        float4 a = *(const float4*)&x[i];
        float4 b = *(const float4*)&x[i + 4];
        ushort8 o;
        o[0] = f2bf(a.x); o[1] = f2bf(a.y); o[2] = f2bf(a.z); o[3] = f2bf(a.w);
        o[4] = f2bf(b.x); o[5] = f2bf(b.y); o[6] = f2bf(b.z); o[7] = f2bf(b.w);
        *(ushort8*)&xb[i] = o;
    } else {
        int i = (bid - 3584) * 256 + tid;  // 0..1535
        float v = (i < 512) ? bq[i] : (i < 1024 ? bk[i - 512] : bv[i - 1024]);
        bqkv[i] = v;
    }
}

// ---------------------------------------------------------------------------
// gemm3: 128x128 tile, BK=64, global_load_lds w=16, XOR-swizzled (proven r10).
// EPI: 1 = bf16 out to C (ldc)
//      3 = qkv split: cols <1024 -> C (ld 1536); cols >=1024 -> vTout[b][d][t]
// ---------------------------------------------------------------------------
template<int EPI>
__global__ __launch_bounds__(256) void gemm3(
    const u16* __restrict__ A, const u16* __restrict__ Bt,
    void* __restrict__ C, const float* __restrict__ bias,
    u16* __restrict__ vTout,
    int lda, int ldb, int ldc, int Kslice, int nsplit, float alpha,
    ll strideA, ll strideB, ll strideC, ll sliceStrideC)
{
    __shared__ __attribute__((aligned(16))) u16 smA[128 * 64];  // 16 KB
    __shared__ __attribute__((aligned(16))) u16 smB[128 * 64];  // 16 KB

    const int z = blockIdx.z;
    const int b = z / nsplit, s = z - b * nsplit;
    A  += (ll)b * strideA + (ll)s * Kslice;
    Bt += (ll)b * strideB + (ll)s * Kslice;
    const ll cbase = (ll)b * strideC + (ll)s * sliceStrideC;

    const int bm = blockIdx.x * 128, bn = blockIdx.y * 128;
    const int t = threadIdx.x, w = t >> 6, l = t & 63;
    const int wm = (w >> 1) * 64, wn = (w & 1) * 64;
    const int lr = l & 15, lg = l >> 4;

    const int srow = l >> 3;
    const int schunk = (l & 7) ^ srow;
    const u16* ga = A + (ll)(bm + w * 32 + srow) * lda + schunk * 8;
    const u16* gb = Bt + (ll)(bn + w * 32 + srow) * ldb + schunk * 8;

    f32x4 acc[4][4] = {};

    for (int k0 = 0; k0 < Kslice; k0 += 64) {
#pragma unroll
        for (int g = 0; g < 4; ++g) {
            GLOAD16(&smA[(w * 32 + g * 8) * 64], ga + (ll)(g * 8) * lda);
            GLOAD16(&smB[(w * 32 + g * 8) * 64], gb + (ll)(g * 8) * ldb);
        }
        ga += 64; gb += 64;
        __syncthreads();

#pragma unroll
        for (int ks = 0; ks < 2; ++ks) {
            bf16x8 af[4], bfr[4];
#pragma unroll
            for (int i = 0; i < 4; ++i) {
                int ra = wm + i * 16 + lr;
                af[i] = *(const bf16x8*)&smA[ra * 64 + ((((ks << 2) | lg)) ^ (ra & 7)) * 8];
            }
#pragma unroll
            for (int i = 0; i < 4; ++i) {
                int rb = wn + i * 16 + lr;
                bfr[i] = *(const bf16x8*)&smB[rb * 64 + ((((ks << 2) | lg)) ^ (rb & 7)) * 8];
            }
#pragma unroll
            for (int mi = 0; mi < 4; ++mi)
#pragma unroll
                for (int ni = 0; ni < 4; ++ni)
                    acc[mi][ni] = __builtin_amdgcn_mfma_f32_16x16x32_bf16(
                        af[mi], bfr[ni], acc[mi][ni], 0, 0, 0);
        }
        __syncthreads();
    }

    const bool addb = (bias != nullptr) && (s == 0);
#pragma unroll
    for (int ni = 0; ni < 4; ++ni) {
        const int col = bn + wn + ni * 16 + lr;
        const float bv = addb ? bias[col] : 0.f;
        const bool vsec = (EPI == 3) && (col >= 1024);   // uniform per ni
#pragma unroll
        for (int mi = 0; mi < 4; ++mi) {
#pragma unroll
            for (int j = 0; j < 4; ++j) {
                const int row = bm + wm + mi * 16 + lg * 4 + j;
                float v = acc[mi][ni][j] * alpha + bv;
                if (vsec) {
                    const int bb = row >> 11, tt = row & 2047;
                    vTout[((ll)bb * 512 + (col - 1024)) * 2048 + tt] = f2bf(v);
                } else {
                    ((u16*)C)[cbase + (ll)row * ldc + col] = f2bf(v);
                }
            }
        }
    }
}

// ---------------------------------------------------------------------------
// gemm256: 256x256 tile, BK=64, 8 waves, double-buffered prefetch (r10 proven).
// EPI: 1 = bf16 out (+bias); 2 = bf16(exp(alpha*v)) + lpart[blockIdx.y][row]
// ---------------------------------------------------------------------------
template<int EPI>
__global__ __launch_bounds__(512, 2) void gemm256(
    const u16* __restrict__ A, const u16* __restrict__ Bt,
    void* __restrict__ C, const float* __restrict__ bias,
    float* __restrict__ lpart,
    int lda, int ldb, int ldc, int K, float alpha,
    ll strideA, ll strideB, ll strideC)
{
    __shared__ __attribute__((aligned(16))) u16 sm[2][2][256 * 64];  // 128 KB

    const int b = blockIdx.z;
    A  += (ll)b * strideA;
    Bt += (ll)b * strideB;
    const ll cbase = (ll)b * strideC;

    const int bm = blockIdx.x * 256, bn = blockIdx.y * 256;
    const int t = threadIdx.x, w = t >> 6, l = t & 63;
    const int wm = (w >> 2) * 128, wn = (w & 3) * 64;
    const int lr = l & 15, lg = l >> 4;

    const int srow = l >> 3;
    const int schunk = (l & 7) ^ srow;
    const u16* ga = A + (ll)(bm + w * 8 + srow) * lda + schunk * 8;
    const u16* gb = Bt + (ll)(bn + w * 8 + srow) * ldb + schunk * 8;

    f32x4 acc[8][4] = {};

    const int nt = K / 64;
#pragma unroll
    for (int g = 0; g < 4; ++g) {
        GLOAD16(&sm[0][0][(g * 64 + w * 8) * 64], ga + (ll)(g * 64) * lda);
        GLOAD16(&sm[0][1][(g * 64 + w * 8) * 64], gb + (ll)(g * 64) * ldb);
    }
    __syncthreads();

    int cur = 0;
    for (int kt = 0; kt < nt; ++kt) {
        if (kt + 1 < nt) {
            const u16* a = ga + (ll)(kt + 1) * 64;
            const u16* bb = gb + (ll)(kt + 1) * 64;
#pragma unroll
            for (int g = 0; g < 4; ++g) {
                GLOAD16(&sm[cur ^ 1][0][(g * 64 + w * 8) * 64], a + (ll)(g * 64) * lda);
                GLOAD16(&sm[cur ^ 1][1][(g * 64 + w * 8) * 64], bb + (ll)(g * 64) * ldb);
            }
        }
#pragma unroll
        for (int ks = 0; ks < 2; ++ks) {
            bf16x8 bfr[4];
#pragma unroll
            for (int ni = 0; ni < 4; ++ni) {
                int rb = wn + ni * 16 + lr;
                bfr[ni] = *(const bf16x8*)&sm[cur][1][rb * 64 + ((((ks << 2) | lg)) ^ (rb & 7)) * 8];
            }
#pragma unroll
            for (int mi = 0; mi < 8; ++mi) {
                int ra = wm + mi * 16 + lr;
                bf16x8 af = *(const bf16x8*)&sm[cur][0][ra * 64 + ((((ks << 2) | lg)) ^ (ra & 7)) * 8];
#pragma unroll
                for (int ni = 0; ni < 4; ++ni)
                    acc[mi][ni] = __builtin_amdgcn_mfma_f32_16x16x32_bf16(
                        af, bfr[ni], acc[mi][ni], 0, 0, 0);
            }
        }
        __syncthreads();
        cur ^= 1;
    }

    // epilogue (r10 original): C/D mapping col = lane&15, row = (lane>>4)*4+j
    const bool addb = (bias != nullptr);
    float rs[8][4] = {};
#pragma unroll
    for (int ni = 0; ni < 4; ++ni) {
        const int col = bn + wn + ni * 16 + lr;
        const float bv = addb ? bias[col] : 0.f;
#pragma unroll
        for (int mi = 0; mi < 8; ++mi) {
#pragma unroll
            for (int j = 0; j < 4; ++j) {
                const int row = bm + wm + mi * 16 + lg * 4 + j;
                float v = acc[mi][ni][j] * alpha + bv;
                if (EPI == 2) { v = __expf(v); rs[mi][j] += v; }
                ((u16*)C)[cbase + (ll)row * ldc + col] = f2bf(v);
            }
        }
    }

    if (EPI == 2) {
        __syncthreads();
        float* lsum = (float*)&sm[0][0][0];   // [4 wn][256 rows]
#pragma unroll
        for (int mi = 0; mi < 8; ++mi)
#pragma unroll
            for (int j = 0; j < 4; ++j) {
                float s2 = rs[mi][j];
                s2 += __shfl_xor(s2, 1);
                s2 += __shfl_xor(s2, 2);
                s2 += __shfl_xor(s2, 4);
                s2 += __shfl_xor(s2, 8);
                if (lr == 0)
                    lsum[(w & 3) * 256 + wm + mi * 16 + lg * 4 + j] = s2;
            }
        __syncthreads();
        if (t < 256)
            lpart[(ll)blockIdx.y * 8192 + (ll)b * 2048 + bm + t] =
                lsum[t] + lsum[256 + t] + lsum[512 + t] + lsum[768 + t];
    }
}

// ---------------------------------------------------------------------------
// hb = bf16( LN(x + (y0+y1+y2+y3)/l) ), l = sum of 8 lpart partials.
// ---------------------------------------------------------------------------
__global__ __launch_bounds__(64) void add_ln_attn(
    const float* __restrict__ x, const u16* __restrict__ yp,
    const float* __restrict__ lpart,
    const float* __restrict__ gamma, const float* __restrict__ beta,
    u16* __restrict__ hb)
{
    ll row = blockIdx.x;
    int l = threadIdx.x;
    float lsum = 0.f;
#pragma unroll
    for (int j = 0; j < 8; ++j) lsum += lpart[j * 8192 + row];  // uniform
    float inv = 1.f / lsum;
    const float* px = x + row * 512;
    float4 x0 = *(const float4*)&px[l * 8], x1 = *(const float4*)&px[l * 8 + 4];
    ushort8 p0 = *(const ushort8*)&yp[row * 512 + l * 8];
    ushort8 p1 = *(const ushort8*)&yp[(ll)1 * 8192 * 512 + row * 512 + l * 8];
    ushort8 p2 = *(const ushort8*)&yp[(ll)2 * 8192 * 512 + row * 512 + l * 8];
    ushort8 p3 = *(const ushort8*)&yp[(ll)3 * 8192 * 512 + row * 512 + l * 8];
    float xa[8] = { x0.x, x0.y, x0.z, x0.w, x1.x, x1.y, x1.z, x1.w };
    float xv[8];
#pragma unroll
    for (int i = 0; i < 8; ++i)
        xv[i] = xa[i] + (bf2f(p0[i]) + bf2f(p1[i]) + bf2f(p2[i]) + bf2f(p3[i])) * inv;
    float s = 0.f, ss = 0.f;
#pragma unroll
    for (int i = 0; i < 8; ++i) { s += xv[i]; ss += xv[i] * xv[i]; }
#pragma unroll
    for (int off = 32; off; off >>= 1) {
        s += __shfl_xor(s, off);
        ss += __shfl_xor(ss, off);
    }
    float mean = s * (1.f / 512.f);
    float var = ss * (1.f / 512.f) - mean * mean;
    float rsq = rsqrtf(var + 1e-14f);
    ushort8 ob;
#pragma unroll
    for (int i = 0; i < 8; ++i)
        ob[i] = f2bf((xv[i] - mean) * rsq * gamma[l * 8 + i] + beta[l * 8 + i]);
    *(ushort8*)&hb[row * 512 + l * 8] = ob;
}

// ---------------------------------------------------------------------------
// out = LN(hb + f0+f1+f2+f3) with bf16 partials; writes fp32 out.
// ---------------------------------------------------------------------------
__global__ __launch_bounds__(64) void add_ln_ffn(
    const u16* __restrict__ hb, const u16* __restrict__ fp,
    const float* __restrict__ gamma, const float* __restrict__ beta,
    float* __restrict__ outf)
{
    ll row = blockIdx.x;
    int l = threadIdx.x;
    ushort8 hh = *(const ushort8*)&hb[row * 512 + l * 8];
    ushort8 p0 = *(const ushort8*)&fp[row * 512 + l * 8];
    ushort8 p1 = *(const ushort8*)&fp[(ll)1 * 8192 * 512 + row * 512 + l * 8];
    ushort8 p2 = *(const ushort8*)&fp[(ll)2 * 8192 * 512 + row * 512 + l * 8];
    ushort8 p3 = *(const ushort8*)&fp[(ll)3 * 8192 * 512 + row * 512 + l * 8];
    float xv[8];
#pragma unroll
    for (int i = 0; i < 8; ++i)
        xv[i] = bf2f(hh[i]) + bf2f(p0[i]) + bf2f(p1[i]) + bf2f(p2[i]) + bf2f(p3[i]);
    float s = 0.f, ss = 0.f;
#pragma unroll
    for (int i = 0; i < 8; ++i) { s += xv[i]; ss += xv[i] * xv[i]; }
#pragma unroll
    for (int off = 32; off; off >>= 1) {
        s += __shfl_xor(s, off);
        ss += __shfl_xor(ss, off);
    }
    float mean = s * (1.f / 512.f);
    float var = ss * (1.f / 512.f) - mean * mean;
    float rsq = rsqrtf(var + 1e-14f);
    float o[8];
#pragma unroll
    for (int i = 0; i < 8; ++i)
        o[i] = (xv[i] - mean) * rsq * gamma[l * 8 + i] + beta[l * 8 + i];
    float4 o0 = { o[0], o[1], o[2], o[3] }, o1 = { o[4], o[5], o[6], o[7] };
    *(float4*)&outf[row * 512 + l * 8] = o0;
    *(float4*)&outf[row * 512 + l * 8 + 4] = o1;
}

// ---------------------------------------------------------------------------
extern "C" void kernel_launch(void* const* d_in, const int* in_sizes, int n_in,
                              void* d_out, int out_size, void* d_ws, size_t ws_size,
                              hipStream_t stream)
{
    const float* x      = (const float*)d_in[0];
    const float* Wq     = (const float*)d_in[1];
    const float* bq     = (const float*)d_in[2];
    const float* Wk     = (const float*)d_in[3];
    const float* bk     = (const float*)d_in[4];
    const float* Wv     = (const float*)d_in[5];
    const float* bv     = (const float*)d_in[6];
    const float* gamma1 = (const float*)d_in[7];
    const float* beta1  = (const float*)d_in[8];
    const float* gamma2 = (const float*)d_in[9];
    const float* beta2  = (const float*)d_in[10];
    const float* W1     = (const float*)d_in[11];
    const float* b1     = (const float*)d_in[12];
    const float* W2     = (const float*)d_in[13];
    const float* b2     = (const float*)d_in[14];

    const int B = 4, S = 2048, D = 512, F = 2048;
    const int BS = B * S;  // 8192

    char* w = (char*)d_ws;
    auto alloc = [&](size_t bytes) {
        char* p = w;
        w += (bytes + 255) & ~(size_t)255;
        return p;
    };
    u16* wqkvT = (u16*)alloc((size_t)3 * D * D * 2);   // [1536][512]
    float* bqkv = (float*)alloc((size_t)3 * D * 4);
    u16* w1T = (u16*)alloc((size_t)F * D * 2);         // [F][D]
    u16* w2T = (u16*)alloc((size_t)D * F * 2);         // [D][F]
    u16* xb  = (u16*)alloc((size_t)BS * D * 2);        // reused as hb
    u16* qkvb = (u16*)alloc((size_t)BS * 3 * D * 2);   // [BS][1536] (v unused)
    u16* attnb = (u16*)alloc((size_t)B * S * S * 2);   // 32MB P~; reused as f1
    u16* vT  = (u16*)alloc((size_t)B * D * S * 2);     // [B][512][2048] 8MB
    u16* ybp = (u16*)alloc((size_t)4 * BS * D * 2);    // 4 partials; reused fp
    float* lpart = (float*)alloc((size_t)8 * BS * 4);  // 256KB row-sum partials

    u16* hb = xb;
    u16* fp = ybp;                                     // FFN2 partials overlay
    u16* f1 = attnb;                                   // [BS,F] bf16 (P~ dead)

    // 1. all preprocessing in one launch
    prep_all<<<dim3(3590), 256, 0, stream>>>(
        Wq, Wk, Wv, wqkvT, W1, w1T, W2, w2T, x, xb, bq, bk, bv, bqkv);
    // 2. qkv = x @ Wqkv^T + bqkv -> qkvb (q,k strided) + vT (v transposed)
    gemm3<3><<<dim3(BS / 128, 3 * D / 128, 1), 256, 0, stream>>>(
        xb, wqkvT, qkvb, bqkv, vT, D, D, 3 * D, D, 1, 1.f, 0, 0, 0, 0);
    // 3. P~ = exp(q @ k^T / 8) -> bf16 + row-sum partials lpart[8][8192]
    gemm256<2><<<dim3(S / 256, S / 256, B), 512, 0, stream>>>(
        qkvb, qkvb + D, attnb, nullptr, lpart, 3 * D, 3 * D, S, D, 0.125f,
        (ll)S * 3 * D, (ll)S * 3 * D, (ll)S * S);
    // 4. y~ = P~ @ v, split-K=4 -> bf16 unnormalized partials ybp[0..3]
    gemm3<1><<<dim3(S / 128, D / 128, B * 4), 256, 0, stream>>>(
        attnb, vT, ybp, nullptr, nullptr, S, S, D, S / 4, 4, 1.f,
        (ll)S * S, (ll)D * S, (ll)S * D, (ll)BS * D);
    // 5. hb = bf16(LN(x + (y0+y1+y2+y3)/l))
    add_ln_attn<<<dim3(BS), 64, 0, stream>>>(x, ybp, lpart, gamma1, beta1, hb);
    // 6. f1 = h @ W1 + b1 (bf16; overlays attnb)
    gemm256<1><<<dim3(BS / 256, F / 256, 1), 512, 0, stream>>>(
        hb, w1T, f1, b1, nullptr, D, D, F, D, 1.f, 0, 0, 0);
    // 7. f2 = f1 @ W2 + b2, split-K=4 -> bf16 partials fp[0..3] (y dead)
    gemm3<1><<<dim3(BS / 128, D / 128, 4), 256, 0, stream>>>(
        f1, w2T, fp, b2, nullptr, F, F, D, F / 4, 4, 1.f, 0, 0, 0,
        (ll)BS * D);
    // 8. out = LN(hb + f0+f1+f2+f3)
    add_ln_ffn<<<dim3(BS), 64, 0, stream>>>(hb, fp, gamma2, beta2,
                                            (float*)d_out);
}

// Round 14
// 174.692 us; speedup vs baseline: 1.0862x; 1.0862x over previous
//
#include <hip/hip_runtime.h>

typedef unsigned short u16;
typedef u16 ushort8 __attribute__((ext_vector_type(8)));
typedef __bf16 bf16x8 __attribute__((ext_vector_type(8)));
typedef float f32x4 __attribute__((ext_vector_type(4)));
typedef long long ll;

__device__ __forceinline__ u16 f2bf(float f) {
    unsigned u = __builtin_bit_cast(unsigned, f);
    u += 0x7FFFu + ((u >> 16) & 1u);
    return (u16)(u >> 16);
}
__device__ __forceinline__ float bf2f(u16 h) {
    return __builtin_bit_cast(float, (unsigned)h << 16);
}

// async global->LDS, 16B per lane, wave-uniform LDS base + lane*16
#define GLOAD16(dst, src) \
    __builtin_amdgcn_global_load_lds( \
        (const __attribute__((address_space(1))) void*)(src), \
        (__attribute__((address_space(3))) void*)(dst), 16, 0, 0)

// ---------------------------------------------------------------------------
// prep_all: one launch for all independent preprocessing (proven).
// ---------------------------------------------------------------------------
__global__ __launch_bounds__(256) void prep_all(
    const float* __restrict__ Wq, const float* __restrict__ Wk,
    const float* __restrict__ Wv, u16* __restrict__ WqkvT,
    const float* __restrict__ W1, u16* __restrict__ w1T,
    const float* __restrict__ W2, u16* __restrict__ w2T,
    const float* __restrict__ x, u16* __restrict__ xb,
    const float* __restrict__ bq, const float* __restrict__ bk,
    const float* __restrict__ bv, float* __restrict__ bqkv)
{
    __shared__ u16 tile[64][65];
    const int bid = blockIdx.x;
    const int tid = threadIdx.x;

    if (bid < 1024) {
        int idx = bid * 256 + tid;              // 0 .. 512*512-1
        int e = idx & 511, d = idx >> 9;
        float sq = 0.f, sk = 0.f, sv = 0.f;
#pragma unroll
        for (int h = 0; h < 8; ++h) {
            ll off = (ll)(h * 512 + d) * 512 + e;
            sq += Wq[off]; sk += Wk[off]; sv += Wv[off];
        }
        int o = e * 512 + d;
        WqkvT[o] = f2bf(sq);
        WqkvT[512 * 512 + o] = f2bf(sk);
        WqkvT[1024 * 512 + o] = f2bf(sv);
    } else if (bid < 1536) {
        const bool isW1 = bid < 1280;
        const int id = isW1 ? (bid - 1024) : (bid - 1280);
        const int bx = isW1 ? (id & 7) : (id & 31);
        const int by = isW1 ? (id >> 3) : (id >> 5);
        const float* in = isW1 ? W1 : W2;
        u16* out = isW1 ? w1T : w2T;
        const int ldin = isW1 ? 2048 : 512;
        const int ldout = isW1 ? 512 : 2048;
        const int r0 = bx * 64, c0 = by * 64;
#pragma unroll
        for (int i = 0; i < 16; ++i) {
            int lin = tid + i * 256;
            int rr = lin >> 6, cc = lin & 63;
            tile[rr][cc] = f2bf(in[(ll)(r0 + rr) * ldin + (c0 + cc)]);
        }
        __syncthreads();
#pragma unroll
        for (int i = 0; i < 16; ++i) {
            int lin = tid + i * 256;
            int rr = lin >> 6, cc = lin & 63;
            out[(ll)(c0 + rr) * ldout + (r0 + cc)] = tile[cc][rr];
        }
    } else if (bid < 3584) {
        ll i = ((ll)(bid - 1536) * 256 + tid) * 8;
        float4 a = *(const float4*)&x[i];
        float4 b = *(const float4*)&x[i + 4];
        ushort8 o;
        o[0] = f2bf(a.x); o[1] = f2bf(a.y); o[2] = f2bf(a.z); o[3] = f2bf(a.w);
        o[4] = f2bf(b.x); o[5] = f2bf(b.y); o[6] = f2bf(b.z); o[7] = f2bf(b.w);
        *(ushort8*)&xb[i] = o;
    } else {
        int i = (bid - 3584) * 256 + tid;  // 0..1535
        float v = (i < 512) ? bq[i] : (i < 1024 ? bk[i - 512] : bv[i - 1024]);
        bqkv[i] = v;
    }
}

// ---------------------------------------------------------------------------
// gemm3: 128x128 tile, BK=64, global_load_lds w=16, XOR-swizzled (proven).
// EPI: 1 = bf16 out to C (ldc)
//      3 = qkv split: cols <1024 -> C (ld 1536); cols >=1024 -> vTout[b][d][t]
// ---------------------------------------------------------------------------
template<int EPI>
__global__ __launch_bounds__(256) void gemm3(
    const u16* __restrict__ A, const u16* __restrict__ Bt,
    void* __restrict__ C, const float* __restrict__ bias,
    u16* __restrict__ vTout,
    int lda, int ldb, int ldc, int Kslice, int nsplit, float alpha,
    ll strideA, ll strideB, ll strideC, ll sliceStrideC)
{
    __shared__ __attribute__((aligned(16))) u16 smA[128 * 64];  // 16 KB
    __shared__ __attribute__((aligned(16))) u16 smB[128 * 64];  // 16 KB

    const int z = blockIdx.z;
    const int b = z / nsplit, s = z - b * nsplit;
    A  += (ll)b * strideA + (ll)s * Kslice;
    Bt += (ll)b * strideB + (ll)s * Kslice;
    const ll cbase = (ll)b * strideC + (ll)s * sliceStrideC;

    const int bm = blockIdx.x * 128, bn = blockIdx.y * 128;
    const int t = threadIdx.x, w = t >> 6, l = t & 63;
    const int wm = (w >> 1) * 64, wn = (w & 1) * 64;
    const int lr = l & 15, lg = l >> 4;

    const int srow = l >> 3;
    const int schunk = (l & 7) ^ srow;
    const u16* ga = A + (ll)(bm + w * 32 + srow) * lda + schunk * 8;
    const u16* gb = Bt + (ll)(bn + w * 32 + srow) * ldb + schunk * 8;

    f32x4 acc[4][4] = {};

    for (int k0 = 0; k0 < Kslice; k0 += 64) {
#pragma unroll
        for (int g = 0; g < 4; ++g) {
            GLOAD16(&smA[(w * 32 + g * 8) * 64], ga + (ll)(g * 8) * lda);
            GLOAD16(&smB[(w * 32 + g * 8) * 64], gb + (ll)(g * 8) * ldb);
        }
        ga += 64; gb += 64;
        __syncthreads();

#pragma unroll
        for (int ks = 0; ks < 2; ++ks) {
            bf16x8 af[4], bfr[4];
#pragma unroll
            for (int i = 0; i < 4; ++i) {
                int ra = wm + i * 16 + lr;
                af[i] = *(const bf16x8*)&smA[ra * 64 + ((((ks << 2) | lg)) ^ (ra & 7)) * 8];
            }
#pragma unroll
            for (int i = 0; i < 4; ++i) {
                int rb = wn + i * 16 + lr;
                bfr[i] = *(const bf16x8*)&smB[rb * 64 + ((((ks << 2) | lg)) ^ (rb & 7)) * 8];
            }
#pragma unroll
            for (int mi = 0; mi < 4; ++mi)
#pragma unroll
                for (int ni = 0; ni < 4; ++ni)
                    acc[mi][ni] = __builtin_amdgcn_mfma_f32_16x16x32_bf16(
                        af[mi], bfr[ni], acc[mi][ni], 0, 0, 0);
        }
        __syncthreads();
    }

    const bool addb = (bias != nullptr) && (s == 0);
#pragma unroll
    for (int ni = 0; ni < 4; ++ni) {
        const int col = bn + wn + ni * 16 + lr;
        const float bv = addb ? bias[col] : 0.f;
        const bool vsec = (EPI == 3) && (col >= 1024);   // uniform per ni
#pragma unroll
        for (int mi = 0; mi < 4; ++mi) {
#pragma unroll
            for (int j = 0; j < 4; ++j) {
                const int row = bm + wm + mi * 16 + lg * 4 + j;
                float v = acc[mi][ni][j] * alpha + bv;
                if (vsec) {
                    const int bb = row >> 11, tt = row & 2047;
                    vTout[((ll)bb * 512 + (col - 1024)) * 2048 + tt] = f2bf(v);
                } else {
                    ((u16*)C)[cbase + (ll)row * ldc + col] = f2bf(v);
                }
            }
        }
    }
}

// ---------------------------------------------------------------------------
// gemm256: 256x256 tile, BK=64, 8 waves, double-buffered prefetch (proven).
// EPI: 1 = bf16 out (+bias); 2 = bf16(exp(alpha*v)) + lpart[blockIdx.y][row]
// ---------------------------------------------------------------------------
template<int EPI>
__global__ __launch_bounds__(512, 2) void gemm256(
    const u16* __restrict__ A, const u16* __restrict__ Bt,
    void* __restrict__ C, const float* __restrict__ bias,
    float* __restrict__ lpart,
    int lda, int ldb, int ldc, int K, float alpha,
    ll strideA, ll strideB, ll strideC)
{
    __shared__ __attribute__((aligned(16))) u16 sm[2][2][256 * 64];  // 128 KB

    const int b = blockIdx.z;
    A  += (ll)b * strideA;
    Bt += (ll)b * strideB;
    const ll cbase = (ll)b * strideC;

    const int bm = blockIdx.x * 256, bn = blockIdx.y * 256;
    const int t = threadIdx.x, w = t >> 6, l = t & 63;
    const int wm = (w >> 2) * 128, wn = (w & 3) * 64;
    const int lr = l & 15, lg = l >> 4;

    const int srow = l >> 3;
    const int schunk = (l & 7) ^ srow;
    const u16* ga = A + (ll)(bm + w * 8 + srow) * lda + schunk * 8;
    const u16* gb = Bt + (ll)(bn + w * 8 + srow) * ldb + schunk * 8;

    f32x4 acc[8][4] = {};

    const int nt = K / 64;
#pragma unroll
    for (int g = 0; g < 4; ++g) {
        GLOAD16(&sm[0][0][(g * 64 + w * 8) * 64], ga + (ll)(g * 64) * lda);
        GLOAD16(&sm[0][1][(g * 64 + w * 8) * 64], gb + (ll)(g * 64) * ldb);
    }
    __syncthreads();

    int cur = 0;
    for (int kt = 0; kt < nt; ++kt) {
        if (kt + 1 < nt) {
            const u16* a = ga + (ll)(kt + 1) * 64;
            const u16* bb = gb + (ll)(kt + 1) * 64;
#pragma unroll
            for (int g = 0; g < 4; ++g) {
                GLOAD16(&sm[cur ^ 1][0][(g * 64 + w * 8) * 64], a + (ll)(g * 64) * lda);
                GLOAD16(&sm[cur ^ 1][1][(g * 64 + w * 8) * 64], bb + (ll)(g * 64) * ldb);
            }
        }
#pragma unroll
        for (int ks = 0; ks < 2; ++ks) {
            bf16x8 bfr[4];
#pragma unroll
            for (int ni = 0; ni < 4; ++ni) {
                int rb = wn + ni * 16 + lr;
                bfr[ni] = *(const bf16x8*)&sm[cur][1][rb * 64 + ((((ks << 2) | lg)) ^ (rb & 7)) * 8];
            }
#pragma unroll
            for (int mi = 0; mi < 8; ++mi) {
                int ra = wm + mi * 16 + lr;
                bf16x8 af = *(const bf16x8*)&sm[cur][0][ra * 64 + ((((ks << 2) | lg)) ^ (ra & 7)) * 8];
#pragma unroll
                for (int ni = 0; ni < 4; ++ni)
                    acc[mi][ni] = __builtin_amdgcn_mfma_f32_16x16x32_bf16(
                        af, bfr[ni], acc[mi][ni], 0, 0, 0);
            }
        }
        __syncthreads();
        cur ^= 1;
    }

    // epilogue: C/D mapping col = lane&15, row = (lane>>4)*4 + j
    const bool addb = (bias != nullptr);
    float rs[8][4] = {};
#pragma unroll
    for (int ni = 0; ni < 4; ++ni) {
        const int col = bn + wn + ni * 16 + lr;
        const float bv = addb ? bias[col] : 0.f;
#pragma unroll
        for (int mi = 0; mi < 8; ++mi) {
#pragma unroll
            for (int j = 0; j < 4; ++j) {
                const int row = bm + wm + mi * 16 + lg * 4 + j;
                float v = acc[mi][ni][j] * alpha + bv;
                if (EPI == 2) { v = __expf(v); rs[mi][j] += v; }
                ((u16*)C)[cbase + (ll)row * ldc + col] = f2bf(v);
            }
        }
    }

    if (EPI == 2) {
        __syncthreads();
        float* lsum = (float*)&sm[0][0][0];   // [4 wn][256 rows]
#pragma unroll
        for (int mi = 0; mi < 8; ++mi)
#pragma unroll
            for (int j = 0; j < 4; ++j) {
                float s2 = rs[mi][j];
                s2 += __shfl_xor(s2, 1);
                s2 += __shfl_xor(s2, 2);
                s2 += __shfl_xor(s2, 4);
                s2 += __shfl_xor(s2, 8);
                if (lr == 0)
                    lsum[(w & 3) * 256 + wm + mi * 16 + lg * 4 + j] = s2;
            }
        __syncthreads();
        if (t < 256)
            lpart[(ll)blockIdx.y * 8192 + (ll)b * 2048 + bm + t] =
                lsum[t] + lsum[256 + t] + lsum[512 + t] + lsum[768 + t];
    }
}

// ---------------------------------------------------------------------------
// hb = bf16( LN(x + (y0+y1)/l) ), l = sum of 8 lpart partials; y0/y1 bf16.
// ---------------------------------------------------------------------------
__global__ __launch_bounds__(64) void add_ln_attn(
    const float* __restrict__ x, const u16* __restrict__ y0,
    const u16* __restrict__ y1, const float* __restrict__ lpart,
    const float* __restrict__ gamma, const float* __restrict__ beta,
    u16* __restrict__ hb)
{
    ll row = blockIdx.x;
    int l = threadIdx.x;
    float lsum = 0.f;
#pragma unroll
    for (int j = 0; j < 8; ++j) lsum += lpart[j * 8192 + row];  // uniform
    float inv = 1.f / lsum;
    const float* px = x + row * 512;
    float4 x0 = *(const float4*)&px[l * 8], x1 = *(const float4*)&px[l * 8 + 4];
    ushort8 a = *(const ushort8*)&y0[row * 512 + l * 8];
    ushort8 bv = *(const ushort8*)&y1[row * 512 + l * 8];
    float xa[8] = { x0.x, x0.y, x0.z, x0.w, x1.x, x1.y, x1.z, x1.w };
    float xv[8];
#pragma unroll
    for (int i = 0; i < 8; ++i)
        xv[i] = xa[i] + (bf2f(a[i]) + bf2f(bv[i])) * inv;
    float s = 0.f, ss = 0.f;
#pragma unroll
    for (int i = 0; i < 8; ++i) { s += xv[i]; ss += xv[i] * xv[i]; }
#pragma unroll
    for (int off = 32; off; off >>= 1) {
        s += __shfl_xor(s, off);
        ss += __shfl_xor(ss, off);
    }
    float mean = s * (1.f / 512.f);
    float var = ss * (1.f / 512.f) - mean * mean;
    float rsq = rsqrtf(var + 1e-14f);
    ushort8 ob;
#pragma unroll
    for (int i = 0; i < 8; ++i)
        ob[i] = f2bf((xv[i] - mean) * rsq * gamma[l * 8 + i] + beta[l * 8 + i]);
    *(ushort8*)&hb[row * 512 + l * 8] = ob;
}

// ---------------------------------------------------------------------------
// out = LN(hb + f0 + f1) with hb/f0/f1 bf16; writes fp32 out.
// ---------------------------------------------------------------------------
__global__ __launch_bounds__(64) void add_ln_ffn(
    const u16* __restrict__ hb, const u16* __restrict__ f0,
    const u16* __restrict__ f1,
    const float* __restrict__ gamma, const float* __restrict__ beta,
    float* __restrict__ outf)
{
    ll row = blockIdx.x;
    int l = threadIdx.x;
    ushort8 hh = *(const ushort8*)&hb[row * 512 + l * 8];
    ushort8 a = *(const ushort8*)&f0[row * 512 + l * 8];
    ushort8 bv = *(const ushort8*)&f1[row * 512 + l * 8];
    float xv[8];
#pragma unroll
    for (int i = 0; i < 8; ++i)
        xv[i] = bf2f(hh[i]) + bf2f(a[i]) + bf2f(bv[i]);
    float s = 0.f, ss = 0.f;
#pragma unroll
    for (int i = 0; i < 8; ++i) { s += xv[i]; ss += xv[i] * xv[i]; }
#pragma unroll
    for (int off = 32; off; off >>= 1) {
        s += __shfl_xor(s, off);
        ss += __shfl_xor(ss, off);
    }
    float mean = s * (1.f / 512.f);
    float var = ss * (1.f / 512.f) - mean * mean;
    float rsq = rsqrtf(var + 1e-14f);
    float o[8];
#pragma unroll
    for (int i = 0; i < 8; ++i)
        o[i] = (xv[i] - mean) * rsq * gamma[l * 8 + i] + beta[l * 8 + i];
    float4 o0 = { o[0], o[1], o[2], o[3] }, o1 = { o[4], o[5], o[6], o[7] };
    *(float4*)&outf[row * 512 + l * 8] = o0;
    *(float4*)&outf[row * 512 + l * 8 + 4] = o1;
}

// ---------------------------------------------------------------------------
extern "C" void kernel_launch(void* const* d_in, const int* in_sizes, int n_in,
                              void* d_out, int out_size, void* d_ws, size_t ws_size,
                              hipStream_t stream)
{
    const float* x      = (const float*)d_in[0];
    const float* Wq     = (const float*)d_in[1];
    const float* bq     = (const float*)d_in[2];
    const float* Wk     = (const float*)d_in[3];
    const float* bk     = (const float*)d_in[4];
    const float* Wv     = (const float*)d_in[5];
    const float* bv     = (const float*)d_in[6];
    const float* gamma1 = (const float*)d_in[7];
    const float* beta1  = (const float*)d_in[8];
    const float* gamma2 = (const float*)d_in[9];
    const float* beta2  = (const float*)d_in[10];
    const float* W1     = (const float*)d_in[11];
    const float* b1     = (const float*)d_in[12];
    const float* W2     = (const float*)d_in[13];
    const float* b2     = (const float*)d_in[14];

    const int B = 4, S = 2048, D = 512, F = 2048;
    const int BS = B * S;  // 8192

    char* w = (char*)d_ws;
    auto alloc = [&](size_t bytes) {
        char* p = w;
        w += (bytes + 255) & ~(size_t)255;
        return p;
    };
    u16* wqkvT = (u16*)alloc((size_t)3 * D * D * 2);   // [1536][512]
    float* bqkv = (float*)alloc((size_t)3 * D * 4);
    u16* w1T = (u16*)alloc((size_t)F * D * 2);         // [F][D]
    u16* w2T = (u16*)alloc((size_t)D * F * 2);         // [D][F]
    u16* xb  = (u16*)alloc((size_t)BS * D * 2);        // reused as hb
    u16* qkvb = (u16*)alloc((size_t)BS * 3 * D * 2);   // [BS][1536] (v unused)
    u16* attnb = (u16*)alloc((size_t)B * S * S * 2);   // 32MB P~; reused as f1
    u16* vT  = (u16*)alloc((size_t)B * D * S * 2);     // [B][512][2048] 8MB
    u16* ybp = (u16*)alloc((size_t)2 * BS * D * 2);    // y~ partials; reused f0/f1p
    float* lpart = (float*)alloc((size_t)8 * BS * 4);  // 256KB row-sum partials

    u16* hb = xb;
    u16* y0b = ybp, * y1b = ybp + (size_t)BS * D;
    u16* f0 = y0b, * f1p = y1b;                        // overlay after y dead
    u16* f1 = attnb;                                   // [BS,F] bf16 (P~ dead)

    // 1. all preprocessing in one launch
    prep_all<<<dim3(3590), 256, 0, stream>>>(
        Wq, Wk, Wv, wqkvT, W1, w1T, W2, w2T, x, xb, bq, bk, bv, bqkv);
    // 2. qkv = x @ Wqkv^T + bqkv -> qkvb (q,k strided) + vT (v transposed)
    gemm3<3><<<dim3(BS / 128, 3 * D / 128, 1), 256, 0, stream>>>(
        xb, wqkvT, qkvb, bqkv, vT, D, D, 3 * D, D, 1, 1.f, 0, 0, 0, 0);
    // 3. P~ = exp(q @ k^T / 8) -> bf16 + row-sum partials lpart[8][8192]
    gemm256<2><<<dim3(S / 256, S / 256, B), 512, 0, stream>>>(
        qkvb, qkvb + D, attnb, nullptr, lpart, 3 * D, 3 * D, S, D, 0.125f,
        (ll)S * 3 * D, (ll)S * 3 * D, (ll)S * S);
    // 4. y~ = P~ @ v, split-K=2 -> bf16 unnormalized partials y0b,y1b
    gemm3<1><<<dim3(S / 128, D / 128, B * 2), 256, 0, stream>>>(
        attnb, vT, y0b, nullptr, nullptr, S, S, D, S / 2, 2, 1.f,
        (ll)S * S, (ll)D * S, (ll)S * D, (ll)BS * D);
    // 5. hb = bf16(LN(x + (y0+y1)/l))
    add_ln_attn<<<dim3(BS), 64, 0, stream>>>(x, y0b, y1b, lpart,
                                             gamma1, beta1, hb);
    // 6. f1 = h @ W1 + b1 (bf16; overlays attnb)
    gemm256<1><<<dim3(BS / 256, F / 256, 1), 512, 0, stream>>>(
        hb, w1T, f1, b1, nullptr, D, D, F, D, 1.f, 0, 0, 0);
    // 7. f2 = f1 @ W2 + b2, split-K=2 -> bf16 partials f0, f1p (y dead)
    gemm3<1><<<dim3(BS / 128, D / 128, 2), 256, 0, stream>>>(
        f1, w2T, f0, b2, nullptr, F, F, D, F / 2, 2, 1.f, 0, 0, 0,
        (ll)BS * D);
    // 8. out = LN(hb + f0 + f1p)
    add_ln_ffn<<<dim3(BS), 64, 0, stream>>>(hb, f0, f1p, gamma2, beta2,
                                            (float*)d_out);
}

// Round 15
// 169.174 us; speedup vs baseline: 1.1216x; 1.0326x over previous
//
#include <hip/hip_runtime.h>

typedef unsigned short u16;
typedef u16 ushort8 __attribute__((ext_vector_type(8)));
typedef __bf16 bf16x8 __attribute__((ext_vector_type(8)));
typedef float f32x4 __attribute__((ext_vector_type(4)));
typedef long long ll;

__device__ __forceinline__ u16 f2bf(float f) {
    unsigned u = __builtin_bit_cast(unsigned, f);
    u += 0x7FFFu + ((u >> 16) & 1u);
    return (u16)(u >> 16);
}
__device__ __forceinline__ float bf2f(u16 h) {
    return __builtin_bit_cast(float, (unsigned)h << 16);
}

// async global->LDS, 16B per lane, wave-uniform LDS base + lane*16
#define GLOAD16(dst, src) \
    __builtin_amdgcn_global_load_lds( \
        (const __attribute__((address_space(1))) void*)(src), \
        (__attribute__((address_space(3))) void*)(dst), 16, 0, 0)

// ---------------------------------------------------------------------------
// prep_all: one launch for all independent preprocessing (proven).
// ---------------------------------------------------------------------------
__global__ __launch_bounds__(256) void prep_all(
    const float* __restrict__ Wq, const float* __restrict__ Wk,
    const float* __restrict__ Wv, u16* __restrict__ WqkvT,
    const float* __restrict__ W1, u16* __restrict__ w1T,
    const float* __restrict__ W2, u16* __restrict__ w2T,
    const float* __restrict__ x, u16* __restrict__ xb,
    const float* __restrict__ bq, const float* __restrict__ bk,
    const float* __restrict__ bv, float* __restrict__ bqkv)
{
    __shared__ u16 tile[64][65];
    const int bid = blockIdx.x;
    const int tid = threadIdx.x;

    if (bid < 1024) {
        int idx = bid * 256 + tid;              // 0 .. 512*512-1
        int e = idx & 511, d = idx >> 9;
        float sq = 0.f, sk = 0.f, sv = 0.f;
#pragma unroll
        for (int h = 0; h < 8; ++h) {
            ll off = (ll)(h * 512 + d) * 512 + e;
            sq += Wq[off]; sk += Wk[off]; sv += Wv[off];
        }
        int o = e * 512 + d;
        WqkvT[o] = f2bf(sq);
        WqkvT[512 * 512 + o] = f2bf(sk);
        WqkvT[1024 * 512 + o] = f2bf(sv);
    } else if (bid < 1536) {
        const bool isW1 = bid < 1280;
        const int id = isW1 ? (bid - 1024) : (bid - 1280);
        const int bx = isW1 ? (id & 7) : (id & 31);
        const int by = isW1 ? (id >> 3) : (id >> 5);
        const float* in = isW1 ? W1 : W2;
        u16* out = isW1 ? w1T : w2T;
        const int ldin = isW1 ? 2048 : 512;
        const int ldout = isW1 ? 512 : 2048;
        const int r0 = bx * 64, c0 = by * 64;
#pragma unroll
        for (int i = 0; i < 16; ++i) {
            int lin = tid + i * 256;
            int rr = lin >> 6, cc = lin & 63;
            tile[rr][cc] = f2bf(in[(ll)(r0 + rr) * ldin + (c0 + cc)]);
        }
        __syncthreads();
#pragma unroll
        for (int i = 0; i < 16; ++i) {
            int lin = tid + i * 256;
            int rr = lin >> 6, cc = lin & 63;
            out[(ll)(c0 + rr) * ldout + (r0 + cc)] = tile[cc][rr];
        }
    } else if (bid < 3584) {
        ll i = ((ll)(bid - 1536) * 256 + tid) * 8;
        float4 a = *(const float4*)&x[i];
        float4 b = *(const float4*)&x[i + 4];
        ushort8 o;
        o[0] = f2bf(a.x); o[1] = f2bf(a.y); o[2] = f2bf(a.z); o[3] = f2bf(a.w);
        o[4] = f2bf(b.x); o[5] = f2bf(b.y); o[6] = f2bf(b.z); o[7] = f2bf(b.w);
        *(ushort8*)&xb[i] = o;
    } else {
        int i = (bid - 3584) * 256 + tid;  // 0..1535
        float v = (i < 512) ? bq[i] : (i < 1024 ? bk[i - 512] : bv[i - 1024]);
        bqkv[i] = v;
    }
}

// ---------------------------------------------------------------------------
// gemm3: 128x128 tile, BK=64, global_load_lds w=16, XOR-swizzled (proven).
// EPI: 1 = bf16 out to C (ldc)
//      3 = qkv split: cols <1024 -> C (ld 1536); cols >=1024 -> vTout[b][d][t]
// ---------------------------------------------------------------------------
template<int EPI>
__global__ __launch_bounds__(256) void gemm3(
    const u16* __restrict__ A, const u16* __restrict__ Bt,
    void* __restrict__ C, const float* __restrict__ bias,
    u16* __restrict__ vTout,
    int lda, int ldb, int ldc, int Kslice, int nsplit, float alpha,
    ll strideA, ll strideB, ll strideC, ll sliceStrideC)
{
    __shared__ __attribute__((aligned(16))) u16 smA[128 * 64];  // 16 KB
    __shared__ __attribute__((aligned(16))) u16 smB[128 * 64];  // 16 KB

    const int z = blockIdx.z;
    const int b = z / nsplit, s = z - b * nsplit;
    A  += (ll)b * strideA + (ll)s * Kslice;
    Bt += (ll)b * strideB + (ll)s * Kslice;
    const ll cbase = (ll)b * strideC + (ll)s * sliceStrideC;

    const int bm = blockIdx.x * 128, bn = blockIdx.y * 128;
    const int t = threadIdx.x, w = t >> 6, l = t & 63;
    const int wm = (w >> 1) * 64, wn = (w & 1) * 64;
    const int lr = l & 15, lg = l >> 4;

    const int srow = l >> 3;
    const int schunk = (l & 7) ^ srow;
    const u16* ga = A + (ll)(bm + w * 32 + srow) * lda + schunk * 8;
    const u16* gb = Bt + (ll)(bn + w * 32 + srow) * ldb + schunk * 8;

    f32x4 acc[4][4] = {};

    for (int k0 = 0; k0 < Kslice; k0 += 64) {
#pragma unroll
        for (int g = 0; g < 4; ++g) {
            GLOAD16(&smA[(w * 32 + g * 8) * 64], ga + (ll)(g * 8) * lda);
            GLOAD16(&smB[(w * 32 + g * 8) * 64], gb + (ll)(g * 8) * ldb);
        }
        ga += 64; gb += 64;
        __syncthreads();

#pragma unroll
        for (int ks = 0; ks < 2; ++ks) {
            bf16x8 af[4], bfr[4];
#pragma unroll
            for (int i = 0; i < 4; ++i) {
                int ra = wm + i * 16 + lr;
                af[i] = *(const bf16x8*)&smA[ra * 64 + ((((ks << 2) | lg)) ^ (ra & 7)) * 8];
            }
#pragma unroll
            for (int i = 0; i < 4; ++i) {
                int rb = wn + i * 16 + lr;
                bfr[i] = *(const bf16x8*)&smB[rb * 64 + ((((ks << 2) | lg)) ^ (rb & 7)) * 8];
            }
#pragma unroll
            for (int mi = 0; mi < 4; ++mi)
#pragma unroll
                for (int ni = 0; ni < 4; ++ni)
                    acc[mi][ni] = __builtin_amdgcn_mfma_f32_16x16x32_bf16(
                        af[mi], bfr[ni], acc[mi][ni], 0, 0, 0);
        }
        __syncthreads();
    }

    const bool addb = (bias != nullptr) && (s == 0);
#pragma unroll
    for (int ni = 0; ni < 4; ++ni) {
        const int col = bn + wn + ni * 16 + lr;
        const float bv = addb ? bias[col] : 0.f;
        const bool vsec = (EPI == 3) && (col >= 1024);   // uniform per ni
#pragma unroll
        for (int mi = 0; mi < 4; ++mi) {
#pragma unroll
            for (int j = 0; j < 4; ++j) {
                const int row = bm + wm + mi * 16 + lg * 4 + j;
                float v = acc[mi][ni][j] * alpha + bv;
                if (vsec) {
                    const int bb = row >> 11, tt = row & 2047;
                    vTout[((ll)bb * 512 + (col - 1024)) * 2048 + tt] = f2bf(v);
                } else {
                    ((u16*)C)[cbase + (ll)row * ldc + col] = f2bf(v);
                }
            }
        }
    }
}

// ---------------------------------------------------------------------------
// gemm3p: gemm3 geometry (128x128, BK=64, 4 waves) + the PROVEN gemm256
// 2-phase double-buffered prefetch loop. LDS 64 KB -> 2 blocks/CU.
// For deep-K shapes (PV, FFN2: 16 K-tiles/slice). bf16 out (+bias on s==0).
// ---------------------------------------------------------------------------
__global__ __launch_bounds__(256) void gemm3p(
    const u16* __restrict__ A, const u16* __restrict__ Bt,
    void* __restrict__ C, const float* __restrict__ bias,
    int lda, int ldb, int ldc, int Kslice, int nsplit, float alpha,
    ll strideA, ll strideB, ll strideC, ll sliceStrideC)
{
    __shared__ __attribute__((aligned(16))) u16 sm[2][2][128 * 64];  // 64 KB

    const int z = blockIdx.z;
    const int b = z / nsplit, s = z - b * nsplit;
    A  += (ll)b * strideA + (ll)s * Kslice;
    Bt += (ll)b * strideB + (ll)s * Kslice;
    const ll cbase = (ll)b * strideC + (ll)s * sliceStrideC;

    const int bm = blockIdx.x * 128, bn = blockIdx.y * 128;
    const int t = threadIdx.x, w = t >> 6, l = t & 63;
    const int wm = (w >> 1) * 64, wn = (w & 1) * 64;
    const int lr = l & 15, lg = l >> 4;

    const int srow = l >> 3;
    const int schunk = (l & 7) ^ srow;
    const u16* ga = A + (ll)(bm + w * 32 + srow) * lda + schunk * 8;
    const u16* gb = Bt + (ll)(bn + w * 32 + srow) * ldb + schunk * 8;

    f32x4 acc[4][4] = {};
    const int nt = Kslice / 64;

    // prologue: stage K-tile 0 into buf 0
#pragma unroll
    for (int g = 0; g < 4; ++g) {
        GLOAD16(&sm[0][0][(w * 32 + g * 8) * 64], ga + (ll)(g * 8) * lda);
        GLOAD16(&sm[0][1][(w * 32 + g * 8) * 64], gb + (ll)(g * 8) * ldb);
    }
    __syncthreads();   // drains vmcnt -> buf0 ready

    int cur = 0;
    for (int kt = 0; kt < nt; ++kt) {
        // issue next-tile stage FIRST (flies under compute)
        if (kt + 1 < nt) {
            const u16* a2 = ga + (ll)(kt + 1) * 64;
            const u16* b2 = gb + (ll)(kt + 1) * 64;
#pragma unroll
            for (int g = 0; g < 4; ++g) {
                GLOAD16(&sm[cur ^ 1][0][(w * 32 + g * 8) * 64], a2 + (ll)(g * 8) * lda);
                GLOAD16(&sm[cur ^ 1][1][(w * 32 + g * 8) * 64], b2 + (ll)(g * 8) * ldb);
            }
        }
        // compute current tile
#pragma unroll
        for (int ks = 0; ks < 2; ++ks) {
            bf16x8 af[4], bfr[4];
#pragma unroll
            for (int i = 0; i < 4; ++i) {
                int ra = wm + i * 16 + lr;
                af[i] = *(const bf16x8*)&sm[cur][0][ra * 64 + ((((ks << 2) | lg)) ^ (ra & 7)) * 8];
            }
#pragma unroll
            for (int i = 0; i < 4; ++i) {
                int rb = wn + i * 16 + lr;
                bfr[i] = *(const bf16x8*)&sm[cur][1][rb * 64 + ((((ks << 2) | lg)) ^ (rb & 7)) * 8];
            }
#pragma unroll
            for (int mi = 0; mi < 4; ++mi)
#pragma unroll
                for (int ni = 0; ni < 4; ++ni)
                    acc[mi][ni] = __builtin_amdgcn_mfma_f32_16x16x32_bf16(
                        af[mi], bfr[ni], acc[mi][ni], 0, 0, 0);
        }
        __syncthreads();   // drains prefetch vmcnt + all reads of buf[cur]
        cur ^= 1;
    }

    const bool addb = (bias != nullptr) && (s == 0);
#pragma unroll
    for (int ni = 0; ni < 4; ++ni) {
        const int col = bn + wn + ni * 16 + lr;
        const float bv = addb ? bias[col] : 0.f;
#pragma unroll
        for (int mi = 0; mi < 4; ++mi) {
#pragma unroll
            for (int j = 0; j < 4; ++j) {
                const int row = bm + wm + mi * 16 + lg * 4 + j;
                float v = acc[mi][ni][j] * alpha + bv;
                ((u16*)C)[cbase + (ll)row * ldc + col] = f2bf(v);
            }
        }
    }
}

// ---------------------------------------------------------------------------
// gemm256: 256x256 tile, BK=64, 8 waves, double-buffered prefetch (proven).
// EPI: 1 = bf16 out (+bias); 2 = bf16(exp(alpha*v)) + lpart[blockIdx.y][row]
// ---------------------------------------------------------------------------
template<int EPI>
__global__ __launch_bounds__(512, 2) void gemm256(
    const u16* __restrict__ A, const u16* __restrict__ Bt,
    void* __restrict__ C, const float* __restrict__ bias,
    float* __restrict__ lpart,
    int lda, int ldb, int ldc, int K, float alpha,
    ll strideA, ll strideB, ll strideC)
{
    __shared__ __attribute__((aligned(16))) u16 sm[2][2][256 * 64];  // 128 KB

    const int b = blockIdx.z;
    A  += (ll)b * strideA;
    Bt += (ll)b * strideB;
    const ll cbase = (ll)b * strideC;

    const int bm = blockIdx.x * 256, bn = blockIdx.y * 256;
    const int t = threadIdx.x, w = t >> 6, l = t & 63;
    const int wm = (w >> 2) * 128, wn = (w & 3) * 64;
    const int lr = l & 15, lg = l >> 4;

    const int srow = l >> 3;
    const int schunk = (l & 7) ^ srow;
    const u16* ga = A + (ll)(bm + w * 8 + srow) * lda + schunk * 8;
    const u16* gb = Bt + (ll)(bn + w * 8 + srow) * ldb + schunk * 8;

    f32x4 acc[8][4] = {};

    const int nt = K / 64;
#pragma unroll
    for (int g = 0; g < 4; ++g) {
        GLOAD16(&sm[0][0][(g * 64 + w * 8) * 64], ga + (ll)(g * 64) * lda);
        GLOAD16(&sm[0][1][(g * 64 + w * 8) * 64], gb + (ll)(g * 64) * ldb);
    }
    __syncthreads();

    int cur = 0;
    for (int kt = 0; kt < nt; ++kt) {
        if (kt + 1 < nt) {
            const u16* a = ga + (ll)(kt + 1) * 64;
            const u16* bb = gb + (ll)(kt + 1) * 64;
#pragma unroll
            for (int g = 0; g < 4; ++g) {
                GLOAD16(&sm[cur ^ 1][0][(g * 64 + w * 8) * 64], a + (ll)(g * 64) * lda);
                GLOAD16(&sm[cur ^ 1][1][(g * 64 + w * 8) * 64], bb + (ll)(g * 64) * ldb);
            }
        }
#pragma unroll
        for (int ks = 0; ks < 2; ++ks) {
            bf16x8 bfr[4];
#pragma unroll
            for (int ni = 0; ni < 4; ++ni) {
                int rb = wn + ni * 16 + lr;
                bfr[ni] = *(const bf16x8*)&sm[cur][1][rb * 64 + ((((ks << 2) | lg)) ^ (rb & 7)) * 8];
            }
#pragma unroll
            for (int mi = 0; mi < 8; ++mi) {
                int ra = wm + mi * 16 + lr;
                bf16x8 af = *(const bf16x8*)&sm[cur][0][ra * 64 + ((((ks << 2) | lg)) ^ (ra & 7)) * 8];
#pragma unroll
                for (int ni = 0; ni < 4; ++ni)
                    acc[mi][ni] = __builtin_amdgcn_mfma_f32_16x16x32_bf16(
                        af, bfr[ni], acc[mi][ni], 0, 0, 0);
            }
        }
        __syncthreads();
        cur ^= 1;
    }

    // epilogue: C/D mapping col = lane&15, row = (lane>>4)*4 + j
    const bool addb = (bias != nullptr);
    float rs[8][4] = {};
#pragma unroll
    for (int ni = 0; ni < 4; ++ni) {
        const int col = bn + wn + ni * 16 + lr;
        const float bv = addb ? bias[col] : 0.f;
#pragma unroll
        for (int mi = 0; mi < 8; ++mi) {
#pragma unroll
            for (int j = 0; j < 4; ++j) {
                const int row = bm + wm + mi * 16 + lg * 4 + j;
                float v = acc[mi][ni][j] * alpha + bv;
                if (EPI == 2) { v = __expf(v); rs[mi][j] += v; }
                ((u16*)C)[cbase + (ll)row * ldc + col] = f2bf(v);
            }
        }
    }

    if (EPI == 2) {
        __syncthreads();
        float* lsum = (float*)&sm[0][0][0];   // [4 wn][256 rows]
#pragma unroll
        for (int mi = 0; mi < 8; ++mi)
#pragma unroll
            for (int j = 0; j < 4; ++j) {
                float s2 = rs[mi][j];
                s2 += __shfl_xor(s2, 1);
                s2 += __shfl_xor(s2, 2);
                s2 += __shfl_xor(s2, 4);
                s2 += __shfl_xor(s2, 8);
                if (lr == 0)
                    lsum[(w & 3) * 256 + wm + mi * 16 + lg * 4 + j] = s2;
            }
        __syncthreads();
        if (t < 256)
            lpart[(ll)blockIdx.y * 8192 + (ll)b * 2048 + bm + t] =
                lsum[t] + lsum[256 + t] + lsum[512 + t] + lsum[768 + t];
    }
}

// ---------------------------------------------------------------------------
// hb = bf16( LN(x + (y0+y1)/l) ), l = sum of 8 lpart partials; y0/y1 bf16.
// ---------------------------------------------------------------------------
__global__ __launch_bounds__(64) void add_ln_attn(
    const float* __restrict__ x, const u16* __restrict__ y0,
    const u16* __restrict__ y1, const float* __restrict__ lpart,
    const float* __restrict__ gamma, const float* __restrict__ beta,
    u16* __restrict__ hb)
{
    ll row = blockIdx.x;
    int l = threadIdx.x;
    float lsum = 0.f;
#pragma unroll
    for (int j = 0; j < 8; ++j) lsum += lpart[j * 8192 + row];  // uniform
    float inv = 1.f / lsum;
    const float* px = x + row * 512;
    float4 x0 = *(const float4*)&px[l * 8], x1 = *(const float4*)&px[l * 8 + 4];
    ushort8 a = *(const ushort8*)&y0[row * 512 + l * 8];
    ushort8 bv = *(const ushort8*)&y1[row * 512 + l * 8];
    float xa[8] = { x0.x, x0.y, x0.z, x0.w, x1.x, x1.y, x1.z, x1.w };
    float xv[8];
#pragma unroll
    for (int i = 0; i < 8; ++i)
        xv[i] = xa[i] + (bf2f(a[i]) + bf2f(bv[i])) * inv;
    float s = 0.f, ss = 0.f;
#pragma unroll
    for (int i = 0; i < 8; ++i) { s += xv[i]; ss += xv[i] * xv[i]; }
#pragma unroll
    for (int off = 32; off; off >>= 1) {
        s += __shfl_xor(s, off);
        ss += __shfl_xor(ss, off);
    }
    float mean = s * (1.f / 512.f);
    float var = ss * (1.f / 512.f) - mean * mean;
    float rsq = rsqrtf(var + 1e-14f);
    ushort8 ob;
#pragma unroll
    for (int i = 0; i < 8; ++i)
        ob[i] = f2bf((xv[i] - mean) * rsq * gamma[l * 8 + i] + beta[l * 8 + i]);
    *(ushort8*)&hb[row * 512 + l * 8] = ob;
}

// ---------------------------------------------------------------------------
// out = LN(hb + f0 + f1) with hb/f0/f1 bf16; writes fp32 out.
// ---------------------------------------------------------------------------
__global__ __launch_bounds__(64) void add_ln_ffn(
    const u16* __restrict__ hb, const u16* __restrict__ f0,
    const u16* __restrict__ f1,
    const float* __restrict__ gamma, const float* __restrict__ beta,
    float* __restrict__ outf)
{
    ll row = blockIdx.x;
    int l = threadIdx.x;
    ushort8 hh = *(const ushort8*)&hb[row * 512 + l * 8];
    ushort8 a = *(const ushort8*)&f0[row * 512 + l * 8];
    ushort8 bv = *(const ushort8*)&f1[row * 512 + l * 8];
    float xv[8];
#pragma unroll
    for (int i = 0; i < 8; ++i)
        xv[i] = bf2f(hh[i]) + bf2f(a[i]) + bf2f(bv[i]);
    float s = 0.f, ss = 0.f;
#pragma unroll
    for (int i = 0; i < 8; ++i) { s += xv[i]; ss += xv[i] * xv[i]; }
#pragma unroll
    for (int off = 32; off; off >>= 1) {
        s += __shfl_xor(s, off);
        ss += __shfl_xor(ss, off);
    }
    float mean = s * (1.f / 512.f);
    float var = ss * (1.f / 512.f) - mean * mean;
    float rsq = rsqrtf(var + 1e-14f);
    float o[8];
#pragma unroll
    for (int i = 0; i < 8; ++i)
        o[i] = (xv[i] - mean) * rsq * gamma[l * 8 + i] + beta[l * 8 + i];
    float4 o0 = { o[0], o[1], o[2], o[3] }, o1 = { o[4], o[5], o[6], o[7] };
    *(float4*)&outf[row * 512 + l * 8] = o0;
    *(float4*)&outf[row * 512 + l * 8 + 4] = o1;
}

// ---------------------------------------------------------------------------
extern "C" void kernel_launch(void* const* d_in, const int* in_sizes, int n_in,
                              void* d_out, int out_size, void* d_ws, size_t ws_size,
                              hipStream_t stream)
{
    const float* x      = (const float*)d_in[0];
    const float* Wq     = (const float*)d_in[1];
    const float* bq     = (const float*)d_in[2];
    const float* Wk     = (const float*)d_in[3];
    const float* bk     = (const float*)d_in[4];
    const float* Wv     = (const float*)d_in[5];
    const float* bv     = (const float*)d_in[6];
    const float* gamma1 = (const float*)d_in[7];
    const float* beta1  = (const float*)d_in[8];
    const float* gamma2 = (const float*)d_in[9];
    const float* beta2  = (const float*)d_in[10];
    const float* W1     = (const float*)d_in[11];
    const float* b1     = (const float*)d_in[12];
    const float* W2     = (const float*)d_in[13];
    const float* b2     = (const float*)d_in[14];

    const int B = 4, S = 2048, D = 512, F = 2048;
    const int BS = B * S;  // 8192

    char* w = (char*)d_ws;
    auto alloc = [&](size_t bytes) {
        char* p = w;
        w += (bytes + 255) & ~(size_t)255;
        return p;
    };
    u16* wqkvT = (u16*)alloc((size_t)3 * D * D * 2);   // [1536][512]
    float* bqkv = (float*)alloc((size_t)3 * D * 4);
    u16* w1T = (u16*)alloc((size_t)F * D * 2);         // [F][D]
    u16* w2T = (u16*)alloc((size_t)D * F * 2);         // [D][F]
    u16* xb  = (u16*)alloc((size_t)BS * D * 2);        // reused as hb
    u16* qkvb = (u16*)alloc((size_t)BS * 3 * D * 2);   // [BS][1536] (v unused)
    u16* attnb = (u16*)alloc((size_t)B * S * S * 2);   // 32MB P~; reused as f1
    u16* vT  = (u16*)alloc((size_t)B * D * S * 2);     // [B][512][2048] 8MB
    u16* ybp = (u16*)alloc((size_t)2 * BS * D * 2);    // y~ partials; reused f0/f1p
    float* lpart = (float*)alloc((size_t)8 * BS * 4);  // 256KB row-sum partials

    u16* hb = xb;
    u16* y0b = ybp, * y1b = ybp + (size_t)BS * D;
    u16* f0 = y0b, * f1p = y1b;                        // overlay after y dead
    u16* f1 = attnb;                                   // [BS,F] bf16 (P~ dead)

    // 1. all preprocessing in one launch
    prep_all<<<dim3(3590), 256, 0, stream>>>(
        Wq, Wk, Wv, wqkvT, W1, w1T, W2, w2T, x, xb, bq, bk, bv, bqkv);
    // 2. qkv = x @ Wqkv^T + bqkv -> qkvb (q,k strided) + vT (v transposed)
    gemm3<3><<<dim3(BS / 128, 3 * D / 128, 1), 256, 0, stream>>>(
        xb, wqkvT, qkvb, bqkv, vT, D, D, 3 * D, D, 1, 1.f, 0, 0, 0, 0);
    // 3. P~ = exp(q @ k^T / 8) -> bf16 + row-sum partials lpart[8][8192]
    gemm256<2><<<dim3(S / 256, S / 256, B), 512, 0, stream>>>(
        qkvb, qkvb + D, attnb, nullptr, lpart, 3 * D, 3 * D, S, D, 0.125f,
        (ll)S * 3 * D, (ll)S * 3 * D, (ll)S * S);
    // 4. y~ = P~ @ v, split-K=2 -> bf16 partials y0b,y1b (prefetch gemm)
    gemm3p<<<dim3(S / 128, D / 128, B * 2), 256, 0, stream>>>(
        attnb, vT, y0b, nullptr, S, S, D, S / 2, 2, 1.f,
        (ll)S * S, (ll)D * S, (ll)S * D, (ll)BS * D);
    // 5. hb = bf16(LN(x + (y0+y1)/l))
    add_ln_attn<<<dim3(BS), 64, 0, stream>>>(x, y0b, y1b, lpart,
                                             gamma1, beta1, hb);
    // 6. f1 = h @ W1 + b1 (bf16; overlays attnb)
    gemm256<1><<<dim3(BS / 256, F / 256, 1), 512, 0, stream>>>(
        hb, w1T, f1, b1, nullptr, D, D, F, D, 1.f, 0, 0, 0);
    // 7. f2 = f1 @ W2 + b2, split-K=2 -> bf16 partials f0, f1p (prefetch gemm)
    gemm3p<<<dim3(BS / 128, D / 128, 2), 256, 0, stream>>>(
        f1, w2T, f0, b2, F, F, D, F / 2, 2, 1.f, 0, 0, 0,
        (ll)BS * D);
    // 8. out = LN(hb + f0 + f1p)
    add_ln_ffn<<<dim3(BS), 64, 0, stream>>>(hb, f0, f1p, gamma2, beta2,
                                            (float*)d_out);
}

// Round 16
// 163.504 us; speedup vs baseline: 1.1605x; 1.0347x over previous
//
#include <hip/hip_runtime.h>

typedef unsigned short u16;
typedef u16 ushort8 __attribute__((ext_vector_type(8)));
typedef __bf16 bf16x8 __attribute__((ext_vector_type(8)));
typedef float f32x4 __attribute__((ext_vector_type(4)));
typedef long long ll;

__device__ __forceinline__ u16 f2bf(float f) {
    unsigned u = __builtin_bit_cast(unsigned, f);
    u += 0x7FFFu + ((u >> 16) & 1u);
    return (u16)(u >> 16);
}
__device__ __forceinline__ float bf2f(u16 h) {
    return __builtin_bit_cast(float, (unsigned)h << 16);
}

// async global->LDS, 16B per lane, wave-uniform LDS base + lane*16
#define GLOAD16(dst, src) \
    __builtin_amdgcn_global_load_lds( \
        (const __attribute__((address_space(1))) void*)(src), \
        (__attribute__((address_space(3))) void*)(dst), 16, 0, 0)

// ---------------------------------------------------------------------------
// prep_all: one launch for all independent preprocessing (proven).
// ---------------------------------------------------------------------------
__global__ __launch_bounds__(256) void prep_all(
    const float* __restrict__ Wq, const float* __restrict__ Wk,
    const float* __restrict__ Wv, u16* __restrict__ WqkvT,
    const float* __restrict__ W1, u16* __restrict__ w1T,
    const float* __restrict__ W2, u16* __restrict__ w2T,
    const float* __restrict__ x, u16* __restrict__ xb,
    const float* __restrict__ bq, const float* __restrict__ bk,
    const float* __restrict__ bv, float* __restrict__ bqkv)
{
    __shared__ u16 tile[64][65];
    const int bid = blockIdx.x;
    const int tid = threadIdx.x;

    if (bid < 1024) {
        int idx = bid * 256 + tid;              // 0 .. 512*512-1
        int e = idx & 511, d = idx >> 9;
        float sq = 0.f, sk = 0.f, sv = 0.f;
#pragma unroll
        for (int h = 0; h < 8; ++h) {
            ll off = (ll)(h * 512 + d) * 512 + e;
            sq += Wq[off]; sk += Wk[off]; sv += Wv[off];
        }
        int o = e * 512 + d;
        WqkvT[o] = f2bf(sq);
        WqkvT[512 * 512 + o] = f2bf(sk);
        WqkvT[1024 * 512 + o] = f2bf(sv);
    } else if (bid < 1536) {
        const bool isW1 = bid < 1280;
        const int id = isW1 ? (bid - 1024) : (bid - 1280);
        const int bx = isW1 ? (id & 7) : (id & 31);
        const int by = isW1 ? (id >> 3) : (id >> 5);
        const float* in = isW1 ? W1 : W2;
        u16* out = isW1 ? w1T : w2T;
        const int ldin = isW1 ? 2048 : 512;
        const int ldout = isW1 ? 512 : 2048;
        const int r0 = bx * 64, c0 = by * 64;
#pragma unroll
        for (int i = 0; i < 16; ++i) {
            int lin = tid + i * 256;
            int rr = lin >> 6, cc = lin & 63;
            tile[rr][cc] = f2bf(in[(ll)(r0 + rr) * ldin + (c0 + cc)]);
        }
        __syncthreads();
#pragma unroll
        for (int i = 0; i < 16; ++i) {
            int lin = tid + i * 256;
            int rr = lin >> 6, cc = lin & 63;
            out[(ll)(c0 + rr) * ldout + (r0 + cc)] = tile[cc][rr];
        }
    } else if (bid < 3584) {
        ll i = ((ll)(bid - 1536) * 256 + tid) * 8;
        float4 a = *(const float4*)&x[i];
        float4 b = *(const float4*)&x[i + 4];
        ushort8 o;
        o[0] = f2bf(a.x); o[1] = f2bf(a.y); o[2] = f2bf(a.z); o[3] = f2bf(a.w);
        o[4] = f2bf(b.x); o[5] = f2bf(b.y); o[6] = f2bf(b.z); o[7] = f2bf(b.w);
        *(ushort8*)&xb[i] = o;
    } else {
        int i = (bid - 3584) * 256 + tid;  // 0..1535
        float v = (i < 512) ? bq[i] : (i < 1024 ? bk[i - 512] : bv[i - 1024]);
        bqkv[i] = v;
    }
}

// ---------------------------------------------------------------------------
// gemm3: 128x128 tile, BK=64, global_load_lds w=16, XOR-swizzled (proven).
// EPI: 1 = bf16 out to C (ldc)
//      3 = qkv split: cols <1024 -> C (ld 1536); cols >=1024 -> vTout[b][d][t]
// ---------------------------------------------------------------------------
template<int EPI>
__global__ __launch_bounds__(256) void gemm3(
    const u16* __restrict__ A, const u16* __restrict__ Bt,
    void* __restrict__ C, const float* __restrict__ bias,
    u16* __restrict__ vTout,
    int lda, int ldb, int ldc, int Kslice, int nsplit, float alpha,
    ll strideA, ll strideB, ll strideC, ll sliceStrideC)
{
    __shared__ __attribute__((aligned(16))) u16 smA[128 * 64];  // 16 KB
    __shared__ __attribute__((aligned(16))) u16 smB[128 * 64];  // 16 KB

    const int z = blockIdx.z;
    const int b = z / nsplit, s = z - b * nsplit;
    A  += (ll)b * strideA + (ll)s * Kslice;
    Bt += (ll)b * strideB + (ll)s * Kslice;
    const ll cbase = (ll)b * strideC + (ll)s * sliceStrideC;

    const int bm = blockIdx.x * 128, bn = blockIdx.y * 128;
    const int t = threadIdx.x, w = t >> 6, l = t & 63;
    const int wm = (w >> 1) * 64, wn = (w & 1) * 64;
    const int lr = l & 15, lg = l >> 4;

    const int srow = l >> 3;
    const int schunk = (l & 7) ^ srow;
    const u16* ga = A + (ll)(bm + w * 32 + srow) * lda + schunk * 8;
    const u16* gb = Bt + (ll)(bn + w * 32 + srow) * ldb + schunk * 8;

    f32x4 acc[4][4] = {};

    for (int k0 = 0; k0 < Kslice; k0 += 64) {
#pragma unroll
        for (int g = 0; g < 4; ++g) {
            GLOAD16(&smA[(w * 32 + g * 8) * 64], ga + (ll)(g * 8) * lda);
            GLOAD16(&smB[(w * 32 + g * 8) * 64], gb + (ll)(g * 8) * ldb);
        }
        ga += 64; gb += 64;
        __syncthreads();

#pragma unroll
        for (int ks = 0; ks < 2; ++ks) {
            bf16x8 af[4], bfr[4];
#pragma unroll
            for (int i = 0; i < 4; ++i) {
                int ra = wm + i * 16 + lr;
                af[i] = *(const bf16x8*)&smA[ra * 64 + ((((ks << 2) | lg)) ^ (ra & 7)) * 8];
            }
#pragma unroll
            for (int i = 0; i < 4; ++i) {
                int rb = wn + i * 16 + lr;
                bfr[i] = *(const bf16x8*)&smB[rb * 64 + ((((ks << 2) | lg)) ^ (rb & 7)) * 8];
            }
#pragma unroll
            for (int mi = 0; mi < 4; ++mi)
#pragma unroll
                for (int ni = 0; ni < 4; ++ni)
                    acc[mi][ni] = __builtin_amdgcn_mfma_f32_16x16x32_bf16(
                        af[mi], bfr[ni], acc[mi][ni], 0, 0, 0);
        }
        __syncthreads();
    }

    const bool addb = (bias != nullptr) && (s == 0);
#pragma unroll
    for (int ni = 0; ni < 4; ++ni) {
        const int col = bn + wn + ni * 16 + lr;
        const float bv = addb ? bias[col] : 0.f;
        const bool vsec = (EPI == 3) && (col >= 1024);   // uniform per ni
#pragma unroll
        for (int mi = 0; mi < 4; ++mi) {
#pragma unroll
            for (int j = 0; j < 4; ++j) {
                const int row = bm + wm + mi * 16 + lg * 4 + j;
                float v = acc[mi][ni][j] * alpha + bv;
                if (vsec) {
                    const int bb = row >> 11, tt = row & 2047;
                    vTout[((ll)bb * 512 + (col - 1024)) * 2048 + tt] = f2bf(v);
                } else {
                    ((u16*)C)[cbase + (ll)row * ldc + col] = f2bf(v);
                }
            }
        }
    }
}

// ---------------------------------------------------------------------------
// gemm3p: 128x128 tile, BK=64, 4 waves, 2-phase double-buffered prefetch
// (r15-proven loop). LDS 64 KB -> 2 blocks/CU.
// EPI: 1 = bf16 out (+bias on s==0)
//      2 = bf16(exp(alpha*v)) + row-sum partials lpart[blockIdx.y][row]
//          (r8/r9-proven epilogue)
// ---------------------------------------------------------------------------
template<int EPI>
__global__ __launch_bounds__(256) void gemm3p(
    const u16* __restrict__ A, const u16* __restrict__ Bt,
    void* __restrict__ C, const float* __restrict__ bias,
    float* __restrict__ lpart,
    int lda, int ldb, int ldc, int Kslice, int nsplit, float alpha,
    ll strideA, ll strideB, ll strideC, ll sliceStrideC)
{
    __shared__ __attribute__((aligned(16))) u16 sm[2][2][128 * 64];  // 64 KB

    const int z = blockIdx.z;
    const int b = z / nsplit, s = z - b * nsplit;
    A  += (ll)b * strideA + (ll)s * Kslice;
    Bt += (ll)b * strideB + (ll)s * Kslice;
    const ll cbase = (ll)b * strideC + (ll)s * sliceStrideC;

    const int bm = blockIdx.x * 128, bn = blockIdx.y * 128;
    const int t = threadIdx.x, w = t >> 6, l = t & 63;
    const int wm = (w >> 1) * 64, wn = (w & 1) * 64;
    const int lr = l & 15, lg = l >> 4;

    const int srow = l >> 3;
    const int schunk = (l & 7) ^ srow;
    const u16* ga = A + (ll)(bm + w * 32 + srow) * lda + schunk * 8;
    const u16* gb = Bt + (ll)(bn + w * 32 + srow) * ldb + schunk * 8;

    f32x4 acc[4][4] = {};
    const int nt = Kslice / 64;

    // prologue: stage K-tile 0 into buf 0
#pragma unroll
    for (int g = 0; g < 4; ++g) {
        GLOAD16(&sm[0][0][(w * 32 + g * 8) * 64], ga + (ll)(g * 8) * lda);
        GLOAD16(&sm[0][1][(w * 32 + g * 8) * 64], gb + (ll)(g * 8) * ldb);
    }
    __syncthreads();   // drains vmcnt -> buf0 ready

    int cur = 0;
    for (int kt = 0; kt < nt; ++kt) {
        // issue next-tile stage FIRST (flies under compute)
        if (kt + 1 < nt) {
            const u16* a2 = ga + (ll)(kt + 1) * 64;
            const u16* b2 = gb + (ll)(kt + 1) * 64;
#pragma unroll
            for (int g = 0; g < 4; ++g) {
                GLOAD16(&sm[cur ^ 1][0][(w * 32 + g * 8) * 64], a2 + (ll)(g * 8) * lda);
                GLOAD16(&sm[cur ^ 1][1][(w * 32 + g * 8) * 64], b2 + (ll)(g * 8) * ldb);
            }
        }
        // compute current tile
#pragma unroll
        for (int ks = 0; ks < 2; ++ks) {
            bf16x8 af[4], bfr[4];
#pragma unroll
            for (int i = 0; i < 4; ++i) {
                int ra = wm + i * 16 + lr;
                af[i] = *(const bf16x8*)&sm[cur][0][ra * 64 + ((((ks << 2) | lg)) ^ (ra & 7)) * 8];
            }
#pragma unroll
            for (int i = 0; i < 4; ++i) {
                int rb = wn + i * 16 + lr;
                bfr[i] = *(const bf16x8*)&sm[cur][1][rb * 64 + ((((ks << 2) | lg)) ^ (rb & 7)) * 8];
            }
#pragma unroll
            for (int mi = 0; mi < 4; ++mi)
#pragma unroll
                for (int ni = 0; ni < 4; ++ni)
                    acc[mi][ni] = __builtin_amdgcn_mfma_f32_16x16x32_bf16(
                        af[mi], bfr[ni], acc[mi][ni], 0, 0, 0);
        }
        __syncthreads();   // drains prefetch vmcnt + all reads of buf[cur]
        cur ^= 1;
    }

    const bool addb = (bias != nullptr) && (s == 0);
    float rs[4][4] = {};   // per-(mi,j) partial row sums (EPI==2 only)
#pragma unroll
    for (int ni = 0; ni < 4; ++ni) {
        const int col = bn + wn + ni * 16 + lr;
        const float bv = addb ? bias[col] : 0.f;
#pragma unroll
        for (int mi = 0; mi < 4; ++mi) {
#pragma unroll
            for (int j = 0; j < 4; ++j) {
                const int row = bm + wm + mi * 16 + lg * 4 + j;
                float v = acc[mi][ni][j] * alpha + bv;
                if (EPI == 2) { v = __expf(v); rs[mi][j] += v; }
                ((u16*)C)[cbase + (ll)row * ldc + col] = f2bf(v);
            }
        }
    }

    if (EPI == 2) {
        // reduce rs across the 16 lr lanes, combine col-half waves via LDS,
        // write one 128-row partial-sum vector per block (r8-proven).
        float* lsum = (float*)&sm[0][0][0];  // safe: K-loop ended with barrier
#pragma unroll
        for (int mi = 0; mi < 4; ++mi)
#pragma unroll
            for (int j = 0; j < 4; ++j) {
                float s2 = rs[mi][j];
                s2 += __shfl_xor(s2, 1);
                s2 += __shfl_xor(s2, 2);
                s2 += __shfl_xor(s2, 4);
                s2 += __shfl_xor(s2, 8);
                if (lr == 0)
                    lsum[(w & 1) * 128 + wm + mi * 16 + lg * 4 + j] = s2;
            }
        __syncthreads();
        if (t < 128)
            lpart[(ll)blockIdx.y * 8192 + (ll)b * 2048 + bm + t] =
                lsum[t] + lsum[128 + t];
    }
}

// ---------------------------------------------------------------------------
// hb = bf16( LN(x + (y0+y1)/l) ), l = sum of 16 lpart partials (r8-proven).
// ---------------------------------------------------------------------------
__global__ __launch_bounds__(64) void add_ln_attn(
    const float* __restrict__ x, const u16* __restrict__ y0,
    const u16* __restrict__ y1, const float* __restrict__ lpart,
    const float* __restrict__ gamma, const float* __restrict__ beta,
    u16* __restrict__ hb)
{
    ll row = blockIdx.x;
    int l = threadIdx.x;
    float lsum = 0.f;
#pragma unroll
    for (int j = 0; j < 16; ++j) lsum += lpart[j * 8192 + row];  // uniform
    float inv = 1.f / lsum;
    const float* px = x + row * 512;
    float4 x0 = *(const float4*)&px[l * 8], x1 = *(const float4*)&px[l * 8 + 4];
    ushort8 a = *(const ushort8*)&y0[row * 512 + l * 8];
    ushort8 bv = *(const ushort8*)&y1[row * 512 + l * 8];
    float xa[8] = { x0.x, x0.y, x0.z, x0.w, x1.x, x1.y, x1.z, x1.w };
    float xv[8];
#pragma unroll
    for (int i = 0; i < 8; ++i)
        xv[i] = xa[i] + (bf2f(a[i]) + bf2f(bv[i])) * inv;
    float s = 0.f, ss = 0.f;
#pragma unroll
    for (int i = 0; i < 8; ++i) { s += xv[i]; ss += xv[i] * xv[i]; }
#pragma unroll
    for (int off = 32; off; off >>= 1) {
        s += __shfl_xor(s, off);
        ss += __shfl_xor(ss, off);
    }
    float mean = s * (1.f / 512.f);
    float var = ss * (1.f / 512.f) - mean * mean;
    float rsq = rsqrtf(var + 1e-14f);
    ushort8 ob;
#pragma unroll
    for (int i = 0; i < 8; ++i)
        ob[i] = f2bf((xv[i] - mean) * rsq * gamma[l * 8 + i] + beta[l * 8 + i]);
    *(ushort8*)&hb[row * 512 + l * 8] = ob;
}

// ---------------------------------------------------------------------------
// out = LN(hb + f0 + f1) with hb/f0/f1 bf16; writes fp32 out.
// ---------------------------------------------------------------------------
__global__ __launch_bounds__(64) void add_ln_ffn(
    const u16* __restrict__ hb, const u16* __restrict__ f0,
    const u16* __restrict__ f1,
    const float* __restrict__ gamma, const float* __restrict__ beta,
    float* __restrict__ outf)
{
    ll row = blockIdx.x;
    int l = threadIdx.x;
    ushort8 hh = *(const ushort8*)&hb[row * 512 + l * 8];
    ushort8 a = *(const ushort8*)&f0[row * 512 + l * 8];
    ushort8 bv = *(const ushort8*)&f1[row * 512 + l * 8];
    float xv[8];
#pragma unroll
    for (int i = 0; i < 8; ++i)
        xv[i] = bf2f(hh[i]) + bf2f(a[i]) + bf2f(bv[i]);
    float s = 0.f, ss = 0.f;
#pragma unroll
    for (int i = 0; i < 8; ++i) { s += xv[i]; ss += xv[i] * xv[i]; }
#pragma unroll
    for (int off = 32; off; off >>= 1) {
        s += __shfl_xor(s, off);
        ss += __shfl_xor(ss, off);
    }
    float mean = s * (1.f / 512.f);
    float var = ss * (1.f / 512.f) - mean * mean;
    float rsq = rsqrtf(var + 1e-14f);
    float o[8];
#pragma unroll
    for (int i = 0; i < 8; ++i)
        o[i] = (xv[i] - mean) * rsq * gamma[l * 8 + i] + beta[l * 8 + i];
    float4 o0 = { o[0], o[1], o[2], o[3] }, o1 = { o[4], o[5], o[6], o[7] };
    *(float4*)&outf[row * 512 + l * 8] = o0;
    *(float4*)&outf[row * 512 + l * 8 + 4] = o1;
}

// ---------------------------------------------------------------------------
extern "C" void kernel_launch(void* const* d_in, const int* in_sizes, int n_in,
                              void* d_out, int out_size, void* d_ws, size_t ws_size,
                              hipStream_t stream)
{
    const float* x      = (const float*)d_in[0];
    const float* Wq     = (const float*)d_in[1];
    const float* bq     = (const float*)d_in[2];
    const float* Wk     = (const float*)d_in[3];
    const float* bk     = (const float*)d_in[4];
    const float* Wv     = (const float*)d_in[5];
    const float* bv     = (const float*)d_in[6];
    const float* gamma1 = (const float*)d_in[7];
    const float* beta1  = (const float*)d_in[8];
    const float* gamma2 = (const float*)d_in[9];
    const float* beta2  = (const float*)d_in[10];
    const float* W1     = (const float*)d_in[11];
    const float* b1     = (const float*)d_in[12];
    const float* W2     = (const float*)d_in[13];
    const float* b2     = (const float*)d_in[14];

    const int B = 4, S = 2048, D = 512, F = 2048;
    const int BS = B * S;  // 8192

    char* w = (char*)d_ws;
    auto alloc = [&](size_t bytes) {
        char* p = w;
        w += (bytes + 255) & ~(size_t)255;
        return p;
    };
    u16* wqkvT = (u16*)alloc((size_t)3 * D * D * 2);   // [1536][512]
    float* bqkv = (float*)alloc((size_t)3 * D * 4);
    u16* w1T = (u16*)alloc((size_t)F * D * 2);         // [F][D]
    u16* w2T = (u16*)alloc((size_t)D * F * 2);         // [D][F]
    u16* xb  = (u16*)alloc((size_t)BS * D * 2);        // reused as hb
    u16* qkvb = (u16*)alloc((size_t)BS * 3 * D * 2);   // [BS][1536] (v unused)
    u16* attnb = (u16*)alloc((size_t)B * S * S * 2);   // 32MB P~; reused as f1
    u16* vT  = (u16*)alloc((size_t)B * D * S * 2);     // [B][512][2048] 8MB
    u16* ybp = (u16*)alloc((size_t)2 * BS * D * 2);    // y~ partials; reused f0/f1p
    float* lpart = (float*)alloc((size_t)16 * BS * 4); // 512KB row-sum partials

    u16* hb = xb;
    u16* y0b = ybp, * y1b = ybp + (size_t)BS * D;
    u16* f0 = y0b, * f1p = y1b;                        // overlay after y dead
    u16* f1 = attnb;                                   // [BS,F] bf16 (P~ dead)

    // 1. all preprocessing in one launch
    prep_all<<<dim3(3590), 256, 0, stream>>>(
        Wq, Wk, Wv, wqkvT, W1, w1T, W2, w2T, x, xb, bq, bk, bv, bqkv);
    // 2. qkv = x @ Wqkv^T + bqkv -> qkvb (q,k strided) + vT (v transposed)
    gemm3<3><<<dim3(BS / 128, 3 * D / 128, 1), 256, 0, stream>>>(
        xb, wqkvT, qkvb, bqkv, vT, D, D, 3 * D, D, 1, 1.f, 0, 0, 0, 0);
    // 3. P~ = exp(q @ k^T / 8) -> bf16 + row-sum partials lpart[16][8192]
    //    (128-tile: no write-amp, r9-proven; + r15-proven prefetch loop)
    gemm3p<2><<<dim3(S / 128, S / 128, B), 256, 0, stream>>>(
        qkvb, qkvb + D, attnb, nullptr, lpart, 3 * D, 3 * D, S, D, 1, 0.125f,
        (ll)S * 3 * D, (ll)S * 3 * D, (ll)S * S, 0);
    // 4. y~ = P~ @ v, split-K=2 -> bf16 partials y0b,y1b (prefetch gemm)
    gemm3p<1><<<dim3(S / 128, D / 128, B * 2), 256, 0, stream>>>(
        attnb, vT, y0b, nullptr, nullptr, S, S, D, S / 2, 2, 1.f,
        (ll)S * S, (ll)D * S, (ll)S * D, (ll)BS * D);
    // 5. hb = bf16(LN(x + (y0+y1)/l))
    add_ln_attn<<<dim3(BS), 64, 0, stream>>>(x, y0b, y1b, lpart,
                                             gamma1, beta1, hb);
    // 6. f1 = h @ W1 + b1 (bf16; overlays attnb; prefetch gemm)
    gemm3p<1><<<dim3(BS / 128, F / 128, 1), 256, 0, stream>>>(
        hb, w1T, f1, b1, nullptr, D, D, F, D, 1, 1.f, 0, 0, 0, 0);
    // 7. f2 = f1 @ W2 + b2, split-K=2 -> bf16 partials f0, f1p (prefetch gemm)
    gemm3p<1><<<dim3(BS / 128, D / 128, 2), 256, 0, stream>>>(
        f1, w2T, f0, b2, nullptr, F, F, D, F / 2, 2, 1.f, 0, 0, 0,
        (ll)BS * D);
    // 8. out = LN(hb + f0 + f1p)
    add_ln_ffn<<<dim3(BS), 64, 0, stream>>>(hb, f0, f1p, gamma2, beta2,
                                            (float*)d_out);
}